// Round 1
// baseline (605.828 us; speedup 1.0000x reference)
//
#include <hip/hip_runtime.h>
#include <math.h>

#define N_NODES 8192
#define FIN 256
#define HDIM 128
#define FOUTD 16
#define KSEL 4096
#define CAP 256   // max row degree capacity (binomial mean ~64, max ~95)

// ---------------------------------------------------------------- CSR build
__global__ void build_csr(const float* __restrict__ A, int* __restrict__ cols,
                          int* __restrict__ deg) {
    int row = blockIdx.x;
    __shared__ int cnt;
    __shared__ int scols[CAP];
    if (threadIdx.x == 0) cnt = 0;
    __syncthreads();
    const float4* Arow = (const float4*)(A + (size_t)row * N_NODES);
    for (int c4 = threadIdx.x; c4 < N_NODES / 4; c4 += blockDim.x) {
        float4 v = Arow[c4];
        int base = c4 * 4;
        if (v.x != 0.0f) { int p = atomicAdd(&cnt, 1); if (p < CAP) scols[p] = base; }
        if (v.y != 0.0f) { int p = atomicAdd(&cnt, 1); if (p < CAP) scols[p] = base + 1; }
        if (v.z != 0.0f) { int p = atomicAdd(&cnt, 1); if (p < CAP) scols[p] = base + 2; }
        if (v.w != 0.0f) { int p = atomicAdd(&cnt, 1); if (p < CAP) scols[p] = base + 3; }
    }
    __syncthreads();
    int c = cnt; if (c > CAP) c = CAP;
    for (int i = threadIdx.x; i < c; i += blockDim.x)
        cols[(size_t)row * CAP + i] = scols[i];
    if (threadIdx.x == 0) deg[row] = c;
}

// ------------------------------------------------- GEMM: Y[N,128] = X@W + b
// optional per-row scale on X (used for the gPool gating xg = h0 * g)
template <int FI>
__global__ void gemm128(const float* __restrict__ X, const float* __restrict__ W,
                        const float* __restrict__ b, const float* __restrict__ scale,
                        float* __restrict__ Y) {
    __shared__ float Xs[8][FI];
    int tid = threadIdx.x;           // 128 threads, one output column each
    int row0 = blockIdx.x * 8;
    for (int i = tid; i < 8 * FI; i += 128) {
        int r = i / FI, k = i - r * FI;
        float v = X[(size_t)(row0 + r) * FI + k];
        if (scale) v *= scale[row0 + r];
        Xs[r][k] = v;
    }
    __syncthreads();
    float acc[8];
    float bias = b[tid];
#pragma unroll
    for (int r = 0; r < 8; r++) acc[r] = bias;
    for (int k = 0; k < FI; k++) {
        float w = W[k * HDIM + tid];
#pragma unroll
        for (int r = 0; r < 8; r++) acc[r] = fmaf(Xs[r][k], w, acc[r]);
    }
#pragma unroll
    for (int r = 0; r < 8; r++) Y[(size_t)(row0 + r) * HDIM + tid] = acc[r];
}

// ------------------------------------------------- GEMM: Y[N,16] = X@W + b
__global__ void gemm16(const float* __restrict__ X, const float* __restrict__ W,
                       const float* __restrict__ b, float* __restrict__ Y) {
    __shared__ float Xs[16][HDIM + 1];
    __shared__ float Ws[HDIM * FOUTD];
    int tid = threadIdx.x;           // 256 threads = 16 rows x 16 cols
    int row0 = blockIdx.x * 16;
    for (int i = tid; i < 16 * HDIM; i += 256) {
        int r = i / HDIM, k = i - r * HDIM;
        Xs[r][k] = X[(size_t)(row0 + r) * HDIM + k];
    }
    for (int i = tid; i < HDIM * FOUTD; i += 256) Ws[i] = W[i];
    __syncthreads();
    int c = tid & 15, r = tid >> 4;
    float acc = b[c];
    for (int k = 0; k < HDIM; k++) acc = fmaf(Xs[r][k], Ws[k * FOUTD + c], acc);
    Y[(size_t)(row0 + r) * FOUTD + c] = acc;
}

// ---------------------- spmm over full graph: OUT[i] = act((T[i]+sum_nbr T[j])/(1+deg))
__global__ void spmm128_full(const float* __restrict__ T, const int* __restrict__ cols,
                             const int* __restrict__ deg, float* __restrict__ OUT,
                             int relu) {
    int row = blockIdx.x;
    int lane = threadIdx.x;          // 128 threads, one feature each
    const int* cl = cols + (size_t)row * CAP;
    int d = deg[row];
    float a0 = 0.f, a1 = 0.f, a2 = 0.f, a3 = 0.f;
    int j = 0;
    for (; j + 4 <= d; j += 4) {
        int c0 = cl[j], c1 = cl[j + 1], c2 = cl[j + 2], c3 = cl[j + 3];
        a0 += T[(size_t)c0 * HDIM + lane];
        a1 += T[(size_t)c1 * HDIM + lane];
        a2 += T[(size_t)c2 * HDIM + lane];
        a3 += T[(size_t)c3 * HDIM + lane];
    }
    for (; j < d; j++) a0 += T[(size_t)cl[j] * HDIM + lane];
    float acc = T[(size_t)row * HDIM + lane] + ((a0 + a1) + (a2 + a3));
    float v = acc / (float)(1 + d);
    if (relu) v = fmaxf(v, 0.f);
    OUT[(size_t)row * HDIM + lane] = v;
}

// ---------------------- pooled spmm: only selected rows/neighbors; zeros elsewhere
__global__ void spmm128_pool(const float* __restrict__ T, const int* __restrict__ cols,
                             const int* __restrict__ deg, const int* __restrict__ sel,
                             float* __restrict__ OUT) {
    int row = blockIdx.x;
    int lane = threadIdx.x;          // 128 threads
    if (!sel[row]) { OUT[(size_t)row * HDIM + lane] = 0.f; return; }
    const int* cl = cols + (size_t)row * CAP;
    int d = deg[row];
    float acc = T[(size_t)row * HDIM + lane];
    int cnt = 0;
    for (int j = 0; j < d; j++) {
        int c = cl[j];
        if (sel[c]) { cnt++; acc += T[(size_t)c * HDIM + lane]; }
    }
    float v = acc / (float)(1 + cnt);
    OUT[(size_t)row * HDIM + lane] = fmaxf(v, 0.f);
}

// ---------------------- score: sraw[i] = dot(h0[i], pw) + pb
__global__ void score_k(const float* __restrict__ H0, const float* __restrict__ pw,
                        const float* __restrict__ pb, float* __restrict__ sraw) {
    int wave = threadIdx.x >> 6, lane = threadIdx.x & 63;
    int row = blockIdx.x * 4 + wave;
    float v = H0[(size_t)row * HDIM + lane] * pw[lane] +
              H0[(size_t)row * HDIM + lane + 64] * pw[lane + 64];
    for (int off = 32; off; off >>= 1) v += __shfl_down(v, off);
    if (lane == 0) sraw[row] = v + pb[0];
}

// ---------------------- top-k (k=4096 of 8192): sel mask + gate value g
__global__ void __launch_bounds__(1024) topk_kernel(const float* __restrict__ sraw,
                                                    int* __restrict__ sel,
                                                    float* __restrict__ g) {
    int tid = threadIdx.x;
    float v[8];
    unsigned key[8];
    float ss = 0.f;
#pragma unroll
    for (int e = 0; e < 8; e++) {
        float x = sraw[tid * 8 + e];
        v[e] = x;
        ss += x * x;
        unsigned b = __float_as_uint(x);
        key[e] = (b & 0x80000000u) ? ~b : (b | 0x80000000u);  // orderable bits
    }
    __shared__ float fred[16];
    __shared__ int ired[16];
    __shared__ float bc_f;
    __shared__ int bc_i;
    // block reduce sum of squares
    for (int off = 32; off; off >>= 1) ss += __shfl_down(ss, off);
    if ((tid & 63) == 0) fred[tid >> 6] = ss;
    __syncthreads();
    if (tid == 0) { float t = 0; for (int i = 0; i < 16; i++) t += fred[i]; bc_f = t; }
    __syncthreads();
    float inv_norm = 1.0f / sqrtf(bc_f);

    // binary search for T = value of k-th largest key: max t with count_ge(t) >= K
    unsigned lo = 0u, hi = 0xFFFFFFFFu;
    while (lo < hi) {
        unsigned mid = lo + ((hi - lo) >> 1) + 1u;
        int c = 0;
#pragma unroll
        for (int e = 0; e < 8; e++) c += (key[e] >= mid);
        for (int off = 32; off; off >>= 1) c += __shfl_down(c, off);
        if ((tid & 63) == 0) ired[tid >> 6] = c;
        __syncthreads();
        if (tid == 0) { int t = 0; for (int i = 0; i < 16; i++) t += ired[i]; bc_i = t; }
        __syncthreads();
        if (bc_i >= KSEL) lo = mid; else hi = mid - 1u;
        __syncthreads();
    }
    unsigned T = lo;
    // count strictly-greater
    int cg = 0;
#pragma unroll
    for (int e = 0; e < 8; e++) cg += (key[e] > T);
    for (int off = 32; off; off >>= 1) cg += __shfl_down(cg, off);
    if ((tid & 63) == 0) ired[tid >> 6] = cg;
    __syncthreads();
    if (tid == 0) { int t = 0; for (int i = 0; i < 16; i++) t += ired[i]; bc_i = t; }
    __syncthreads();
    int need = KSEL - bc_i;
    // exclusive prefix scan of per-thread equal-counts (tie-break by lowest index)
    int eq = 0;
#pragma unroll
    for (int e = 0; e < 8; e++) eq += (key[e] == T);
    __shared__ int sc[1024];
    sc[tid] = eq;
    __syncthreads();
    for (int off = 1; off < 1024; off <<= 1) {
        int val = (tid >= off) ? sc[tid - off] : 0;
        __syncthreads();
        sc[tid] += val;
        __syncthreads();
    }
    int excl = sc[tid] - eq;
    int seen = 0;
#pragma unroll
    for (int e = 0; e < 8; e++) {
        int i = tid * 8 + e;
        int s;
        if (key[e] > T) s = 1;
        else if (key[e] == T) { s = (excl + seen < need) ? 1 : 0; seen++; }
        else s = 0;
        sel[i] = s;
        g[i] = s ? (1.0f / (1.0f + expf(-(v[e] * inv_norm)))) : 0.0f;
    }
}

// ---------------------- final: spmm F=16 + log_softmax
__global__ void spmm16_lsm(const float* __restrict__ T3, const int* __restrict__ cols,
                           const int* __restrict__ deg, float* __restrict__ out) {
    int lane = threadIdx.x;          // 64 = 4 rows x 16 cols
    int r = lane >> 4, c = lane & 15;
    int row = blockIdx.x * 4 + r;
    const int* cl = cols + (size_t)row * CAP;
    int d = deg[row];
    float acc = T3[(size_t)row * FOUTD + c];
    for (int j = 0; j < d; j++) acc += T3[(size_t)cl[j] * FOUTD + c];
    float v = acc / (float)(1 + d);
    float m = v;
    for (int off = 1; off < 16; off <<= 1) m = fmaxf(m, __shfl_xor(m, off, 16));
    float e = expf(v - m);
    float s = e;
    for (int off = 1; off < 16; off <<= 1) s += __shfl_xor(s, off, 16);
    out[(size_t)row * FOUTD + c] = v - m - logf(s);
}

// ------------------------------------------------------------------ launch
extern "C" void kernel_launch(void* const* d_in, const int* in_sizes, int n_in,
                              void* d_out, int out_size, void* d_ws, size_t ws_size,
                              hipStream_t stream) {
    const float* x  = (const float*)d_in[0];
    const float* A  = (const float*)d_in[1];
    const float* W0 = (const float*)d_in[2];
    const float* b0 = (const float*)d_in[3];
    const float* W1 = (const float*)d_in[4];
    const float* b1 = (const float*)d_in[5];
    const float* pw = (const float*)d_in[6];
    const float* pb = (const float*)d_in[7];
    const float* Wu = (const float*)d_in[8];
    const float* bu = (const float*)d_in[9];
    const float* Wf = (const float*)d_in[10];
    const float* bf = (const float*)d_in[11];
    float* out = (float*)d_out;

    char* ws = (char*)d_ws;
    int*   cols = (int*)  (ws);                               // 8 MB
    int*   deg  = (int*)  (ws + 8388608);                     // 32 KB
    float* T    = (float*)(ws + 8421376);                     // 4 MB (t0/t1/t2)
    float* H0   = (float*)(ws + 12615680);                    // 4 MB (h0, later hu)
    float* XU   = (float*)(ws + 16809984);                    // 4 MB
    float* T3   = (float*)(ws + 21004288);                    // 512 KB
    float* sraw = (float*)(ws + 21528576);                    // 32 KB
    int*   sel  = (int*)  (ws + 21561344);                    // 32 KB
    float* g    = (float*)(ws + 21594112);                    // 32 KB

    // 1. CSR of A
    build_csr<<<N_NODES, 256, 0, stream>>>(A, cols, deg);
    // 2. t0 = x@W0 + b0
    gemm128<FIN><<<N_NODES / 8, 128, 0, stream>>>(x, W0, b0, nullptr, T);
    // 3. h0 = relu(norm_adj(A) @ t0)
    spmm128_full<<<N_NODES, 128, 0, stream>>>(T, cols, deg, H0, 1);
    // 4. raw score
    score_k<<<N_NODES / 4, 256, 0, stream>>>(H0, pw, pb, sraw);
    // 5. top-k -> sel mask + gate g = sigmoid(s/||s||)
    topk_kernel<<<1, 1024, 0, stream>>>(sraw, sel, g);
    // 6. t1 = (h0*g)@W1 + b1   (row scale applies gating)
    gemm128<HDIM><<<N_NODES / 8, 128, 0, stream>>>(H0, W1, b1, g, T);
    // 7. xu = scatter(relu(norm_adj(Ap) @ t1))  (zeros on unselected rows)
    spmm128_pool<<<N_NODES, 128, 0, stream>>>(T, cols, deg, sel, XU);
    // 8. t2 = xu@Wu + bu
    gemm128<HDIM><<<N_NODES / 8, 128, 0, stream>>>(XU, Wu, bu, nullptr, T);
    // 9. hu = relu(norm_adj(A) @ t2)   (reuse H0)
    spmm128_full<<<N_NODES, 128, 0, stream>>>(T, cols, deg, H0, 1);
    // 10. t3 = hu@Wf + bf
    gemm16<<<N_NODES / 16, 256, 0, stream>>>(H0, Wf, bf, T3);
    // 11. hf = norm_adj(A) @ t3; out = log_softmax(hf)
    spmm16_lsm<<<N_NODES / 4, 64, 0, stream>>>(T3, cols, deg, out);
}

// Round 2
// 594.462 us; speedup vs baseline: 1.0191x; 1.0191x over previous
//
#include <hip/hip_runtime.h>
#include <math.h>

#define N_NODES 8192
#define FIN 256
#define HDIM 128
#define FOUTD 16
#define KSEL 4096
#define CAP 128   // max row degree capacity (Binom mean ~64, sd ~8; 128 = +8 sd)

typedef unsigned int uint;
typedef unsigned short ushort;

static __device__ __forceinline__ ushort f2bf(float f) {
    uint u = __float_as_uint(f);
    return (ushort)((u + 0x7FFFu + ((u >> 16) & 1u)) >> 16);   // RNE, no NaN expected
}
static __device__ __forceinline__ float bf_lo(uint u) { return __uint_as_float(u << 16); }
static __device__ __forceinline__ float bf_hi(uint u) { return __uint_as_float(u & 0xFFFF0000u); }

// ---------------------------------------------------------------- CSR build
__global__ __launch_bounds__(256) void build_csr(const float* __restrict__ A,
                                                 int* __restrict__ cols,
                                                 int* __restrict__ deg) {
    int row = blockIdx.x;
    __shared__ int cnt;
    __shared__ int scols[CAP];
    if (threadIdx.x == 0) cnt = 0;
    __syncthreads();
    const float4* Arow = (const float4*)(A + (size_t)row * N_NODES);
    for (int c4 = threadIdx.x; c4 < N_NODES / 4; c4 += blockDim.x) {
        float4 v = Arow[c4];
        int base = c4 * 4;
        if (v.x != 0.0f) { int p = atomicAdd(&cnt, 1); if (p < CAP) scols[p] = base; }
        if (v.y != 0.0f) { int p = atomicAdd(&cnt, 1); if (p < CAP) scols[p] = base + 1; }
        if (v.z != 0.0f) { int p = atomicAdd(&cnt, 1); if (p < CAP) scols[p] = base + 2; }
        if (v.w != 0.0f) { int p = atomicAdd(&cnt, 1); if (p < CAP) scols[p] = base + 3; }
    }
    __syncthreads();
    int c = cnt; if (c > CAP) c = CAP;
    for (int i = threadIdx.x; i < c; i += blockDim.x)
        cols[(size_t)row * CAP + i] = scols[i];
    if (threadIdx.x == 0) deg[row] = c;
}

// ------------------------------------------- GEMM: Y[8r,128] = X@W (+scale)+b
// No LDS: X rows read via wave-uniform addresses (scalar loads), W coalesced.
template <int FI, int OUT_BF16>
__global__ __launch_bounds__(128) void gemm_t(const float* __restrict__ X,
                                              const float* __restrict__ W,
                                              const float* __restrict__ b,
                                              const float* __restrict__ scale,
                                              void* __restrict__ Y) {
    int tid = threadIdx.x;
    int row0 = blockIdx.x * 8;
    float acc[8];
#pragma unroll
    for (int r = 0; r < 8; r++) acc[r] = 0.0f;
    const float* Xb = X + (size_t)row0 * FI;
    for (int k = 0; k < FI; k += 4) {
        float w0 = W[(k + 0) * HDIM + tid];
        float w1 = W[(k + 1) * HDIM + tid];
        float w2 = W[(k + 2) * HDIM + tid];
        float w3 = W[(k + 3) * HDIM + tid];
#pragma unroll
        for (int r = 0; r < 8; r++) {
            const float* xr = Xb + r * FI + k;   // wave-uniform -> s_load
            acc[r] = fmaf(xr[0], w0, acc[r]);
            acc[r] = fmaf(xr[1], w1, acc[r]);
            acc[r] = fmaf(xr[2], w2, acc[r]);
            acc[r] = fmaf(xr[3], w3, acc[r]);
        }
    }
    float bias = b[tid];
#pragma unroll
    for (int r = 0; r < 8; r++) {
        float sc = scale ? scale[row0 + r] : 1.0f;
        float val = fmaf(acc[r], sc, bias);
        if (OUT_BF16) ((ushort*)Y)[(size_t)(row0 + r) * HDIM + tid] = f2bf(val);
        else          ((float*)Y)[(size_t)(row0 + r) * HDIM + tid] = val;
    }
}

// ------------- spmm over full graph (fp32) + fused pooling score
__global__ __launch_bounds__(128) void spmm_score(const float* __restrict__ T0,
                                                  const int* __restrict__ cols,
                                                  const int* __restrict__ deg,
                                                  const float* __restrict__ pw,
                                                  const float* __restrict__ pb,
                                                  float* __restrict__ H0,
                                                  float* __restrict__ sraw) {
    int row = blockIdx.x;
    int lane = threadIdx.x;
    const int* cl = cols + (size_t)row * CAP;
    int d = deg[row];
    float a0 = 0.f, a1 = 0.f, a2 = 0.f, a3 = 0.f;
    int j = 0;
    for (; j + 4 <= d; j += 4) {
        int c0 = cl[j], c1 = cl[j + 1], c2 = cl[j + 2], c3 = cl[j + 3];
        a0 += T0[(size_t)c0 * HDIM + lane];
        a1 += T0[(size_t)c1 * HDIM + lane];
        a2 += T0[(size_t)c2 * HDIM + lane];
        a3 += T0[(size_t)c3 * HDIM + lane];
    }
    for (; j < d; j++) a0 += T0[(size_t)cl[j] * HDIM + lane];
    float acc = T0[(size_t)row * HDIM + lane] + ((a0 + a1) + (a2 + a3));
    float h = fmaxf(acc / (float)(1 + d), 0.f);
    H0[(size_t)row * HDIM + lane] = h;
    // score dot
    float v = h * pw[lane];
    for (int off = 32; off; off >>= 1) v += __shfl_down(v, off);
    __shared__ float ws2[2];
    if ((lane & 63) == 0) ws2[lane >> 6] = v;
    __syncthreads();
    if (lane == 0) sraw[row] = ws2[0] + ws2[1] + pb[0];
}

// ---------------------- top-k (4096 of 8192) via 4-pass 8-bit radix select
__global__ __launch_bounds__(256) void topk_radix(const float* __restrict__ sraw,
                                                  int* __restrict__ sel,
                                                  float* __restrict__ g) {
    int tid = threadIdx.x;
    float v[32];
    unsigned key[32];
    float ss = 0.f;
#pragma unroll
    for (int e = 0; e < 32; e++) {
        float x = sraw[tid * 32 + e];
        v[e] = x; ss += x * x;
        unsigned b = __float_as_uint(x);
        key[e] = (b & 0x80000000u) ? ~b : (b | 0x80000000u);
    }
    __shared__ float fr[4];
    __shared__ float bss;
    for (int off = 32; off; off >>= 1) ss += __shfl_down(ss, off);
    if ((tid & 63) == 0) fr[tid >> 6] = ss;
    __syncthreads();
    if (tid == 0) bss = fr[0] + fr[1] + fr[2] + fr[3];
    __syncthreads();
    float inv_norm = 1.0f / sqrtf(bss);

    __shared__ int hist[256];
    __shared__ int sfx[256];
    __shared__ int bd, bkneed;
    unsigned prefix = 0; int kneed = KSEL;
    for (int pass = 0; pass < 4; pass++) {
        int shift = 24 - 8 * pass;
        unsigned maskAbove = (pass == 0) ? 0u : (0xFFFFFFFFu << (shift + 8));
        hist[tid] = 0;
        __syncthreads();
#pragma unroll
        for (int e = 0; e < 32; e++)
            if ((key[e] & maskAbove) == prefix)
                atomicAdd(&hist[(key[e] >> shift) & 255], 1);
        __syncthreads();
        sfx[tid] = hist[tid];
        __syncthreads();
        for (int off = 1; off < 256; off <<= 1) {
            int add = (tid + off < 256) ? sfx[tid + off] : 0;
            __syncthreads();
            sfx[tid] += add;
            __syncthreads();
        }
        int s_here = sfx[tid];
        int s_next = (tid < 255) ? sfx[tid + 1] : 0;
        if (s_here >= kneed && s_next < kneed) { bd = tid; bkneed = kneed - s_next; }
        __syncthreads();
        prefix |= ((unsigned)bd) << shift;
        kneed = bkneed;
        __syncthreads();
    }
    unsigned T = prefix;
    // tie-break by lowest index among keys == T
    int eq = 0;
#pragma unroll
    for (int e = 0; e < 32; e++) eq += (key[e] == T);
    __shared__ int sc[256];
    sc[tid] = eq;
    __syncthreads();
    for (int off = 1; off < 256; off <<= 1) {
        int add = (tid >= off) ? sc[tid - off] : 0;
        __syncthreads();
        sc[tid] += add;
        __syncthreads();
    }
    int excl = sc[tid] - eq;
    int seen = 0;
#pragma unroll
    for (int e = 0; e < 32; e++) {
        int i = tid * 32 + e;
        int s;
        if (key[e] > T) s = 1;
        else if (key[e] == T) { s = (excl + seen < kneed) ? 1 : 0; seen++; }
        else s = 0;
        sel[i] = s;
        g[i] = s ? (1.0f / (1.0f + expf(-(v[e] * inv_norm)))) : 0.0f;
    }
}

// -------- fused: pooled spmm over T1(bf16) -> xu row -> t2 = xu@Wu+bu (bf16)
__global__ __launch_bounds__(64) void pool_gemm(const uint* __restrict__ T1u,
                                                const int* __restrict__ cols,
                                                const int* __restrict__ deg,
                                                const int* __restrict__ sel,
                                                const float* __restrict__ Wu,
                                                const float* __restrict__ bu,
                                                uint* __restrict__ T2u) {
    int row = blockIdx.x;
    int t = threadIdx.x;   // owns features/cols 2t, 2t+1
    float2 bias = ((const float2*)bu)[t];
    if (!sel[row]) {   // xu row = 0 -> t2 = bu
        T2u[(size_t)row * 64 + t] = (uint)f2bf(bias.x) | ((uint)f2bf(bias.y) << 16);
        return;
    }
    const int* cl = cols + (size_t)row * CAP;
    int d = deg[row];
    uint su = T1u[(size_t)row * 64 + t];
    float ax = bf_lo(su), ay = bf_hi(su);
    int cnt = 0;
    for (int j = 0; j < d; j++) {
        int c = cl[j];
        if (sel[c]) {
            cnt++;
            uint u = T1u[(size_t)c * 64 + t];
            ax += bf_lo(u); ay += bf_hi(u);
        }
    }
    float inv = 1.0f / (float)(1 + cnt);
    float xux = fmaxf(ax * inv, 0.f);   // xu[2t]
    float xuy = fmaxf(ay * inv, 0.f);   // xu[2t+1]
    // t2[c] = sum_k xu[k]*Wu[k][c] + bu[c]
    float accx = bias.x, accy = bias.y;
    const float2* Wur = (const float2*)Wu;   // [128][64] pairs
#pragma unroll 4
    for (int kk = 0; kk < 64; kk++) {
        float xk0 = __uint_as_float(__builtin_amdgcn_readlane(__float_as_uint(xux), kk));
        float xk1 = __uint_as_float(__builtin_amdgcn_readlane(__float_as_uint(xuy), kk));
        float2 w0 = Wur[(size_t)(2 * kk) * 64 + t];
        float2 w1 = Wur[(size_t)(2 * kk + 1) * 64 + t];
        accx = fmaf(xk0, w0.x, accx); accy = fmaf(xk0, w0.y, accy);
        accx = fmaf(xk1, w1.x, accx); accy = fmaf(xk1, w1.y, accy);
    }
    T2u[(size_t)row * 64 + t] = (uint)f2bf(accx) | ((uint)f2bf(accy) << 16);
}

// -------- fused: full spmm over T2(bf16) -> hu -> t3 = hu@Wf+bf (fp32, F=16)
__global__ __launch_bounds__(64) void up_gemm16(const uint* __restrict__ T2u,
                                                const int* __restrict__ cols,
                                                const int* __restrict__ deg,
                                                const float* __restrict__ Wf,
                                                const float* __restrict__ bf_,
                                                float* __restrict__ T3) {
    int row = blockIdx.x;
    int t = threadIdx.x;
    const int* cl = cols + (size_t)row * CAP;
    int d = deg[row];
    uint su = T2u[(size_t)row * 64 + t];
    float ax = bf_lo(su), ay = bf_hi(su);
    for (int j = 0; j < d; j++) {
        uint u = T2u[(size_t)cl[j] * 64 + t];
        ax += bf_lo(u); ay += bf_hi(u);
    }
    float inv = 1.0f / (float)(1 + d);
    float hux = fmaxf(ax * inv, 0.f);
    float huy = fmaxf(ay * inv, 0.f);
    __shared__ float hs[128];
    hs[2 * t] = hux; hs[2 * t + 1] = huy;
    __syncthreads();
    int c = t & 15, gg = t >> 4;   // 4 k-groups x 16 cols
    float p = 0.f;
#pragma unroll 8
    for (int kk = 0; kk < 32; kk++) {
        int k = gg * 32 + kk;
        p = fmaf(hs[k], Wf[k * FOUTD + c], p);
    }
    p += __shfl_xor(p, 16);
    p += __shfl_xor(p, 32);
    if (t < 16) T3[(size_t)row * FOUTD + t] = p + bf_[t];
}

// ---------------------- final: spmm F=16 + log_softmax
__global__ __launch_bounds__(64) void spmm16_lsm(const float* __restrict__ T3,
                                                 const int* __restrict__ cols,
                                                 const int* __restrict__ deg,
                                                 float* __restrict__ out) {
    int lane = threadIdx.x;          // 64 = 4 rows x 16 cols
    int r = lane >> 4, c = lane & 15;
    int row = blockIdx.x * 4 + r;
    const int* cl = cols + (size_t)row * CAP;
    int d = deg[row];
    float acc = T3[(size_t)row * FOUTD + c];
    for (int j = 0; j < d; j++) acc += T3[(size_t)cl[j] * FOUTD + c];
    float v = acc / (float)(1 + d);
    float m = v;
    for (int off = 1; off < 16; off <<= 1) m = fmaxf(m, __shfl_xor(m, off, 16));
    float e = expf(v - m);
    float s = e;
    for (int off = 1; off < 16; off <<= 1) s += __shfl_xor(s, off, 16);
    out[(size_t)row * FOUTD + c] = v - m - logf(s);
}

// ------------------------------------------------------------------ launch
extern "C" void kernel_launch(void* const* d_in, const int* in_sizes, int n_in,
                              void* d_out, int out_size, void* d_ws, size_t ws_size,
                              hipStream_t stream) {
    const float* x  = (const float*)d_in[0];
    const float* A  = (const float*)d_in[1];
    const float* W0 = (const float*)d_in[2];
    const float* b0 = (const float*)d_in[3];
    const float* W1 = (const float*)d_in[4];
    const float* b1 = (const float*)d_in[5];
    const float* pw = (const float*)d_in[6];
    const float* pb = (const float*)d_in[7];
    const float* Wu = (const float*)d_in[8];
    const float* bu = (const float*)d_in[9];
    const float* Wf = (const float*)d_in[10];
    const float* bf = (const float*)d_in[11];
    float* out = (float*)d_out;

    char* ws = (char*)d_ws;
    const size_t MB = 1024 * 1024;
    int*   cols = (int*)  (ws);              // 4 MB
    int*   deg  = (int*)  (ws + 4  * MB);    // 32 KB
    float* T0   = (float*)(ws + 5  * MB);    // 4 MB fp32
    float* H0   = (float*)(ws + 9  * MB);    // 4 MB fp32
    uint*  T1   = (uint*) (ws + 13 * MB);    // 2 MB bf16
    uint*  T2   = (uint*) (ws + 15 * MB);    // 2 MB bf16
    float* T3   = (float*)(ws + 17 * MB);    // 512 KB fp32
    float* sraw = (float*)(ws + 18 * MB);    // 32 KB
    int*   sel  = (int*)  (ws + 18 * MB + 512 * 1024);
    float* g    = (float*)(ws + 19 * MB);

    // 1. CSR of A
    build_csr<<<N_NODES, 256, 0, stream>>>(A, cols, deg);
    // 2. t0 = x@W0 + b0 (fp32)
    gemm_t<FIN, 0><<<N_NODES / 8, 128, 0, stream>>>(x, W0, b0, nullptr, T0);
    // 3. h0 = relu(norm_adj(A)@t0)  + raw score (fp32 -> exact selection)
    spmm_score<<<N_NODES, 128, 0, stream>>>(T0, cols, deg, pw, pb, H0, sraw);
    // 4. top-k radix select -> sel, g
    topk_radix<<<1, 256, 0, stream>>>(sraw, sel, g);
    // 5. t1 = (h0*g)@W1 + b1  (bf16 out)
    gemm_t<HDIM, 1><<<N_NODES / 8, 128, 0, stream>>>(H0, W1, b1, g, (void*)T1);
    // 6. xu = scatter(relu(norm_adj(Ap)@t1)); t2 = xu@Wu + bu (bf16)
    pool_gemm<<<N_NODES, 64, 0, stream>>>(T1, cols, deg, sel, Wu, bu, T2);
    // 7. hu = relu(norm_adj(A)@t2); t3 = hu@Wf + bf (fp32)
    up_gemm16<<<N_NODES, 64, 0, stream>>>(T2, cols, deg, Wf, bf, T3);
    // 8. hf = norm_adj(A)@t3; out = log_softmax(hf)
    spmm16_lsm<<<N_NODES / 4, 64, 0, stream>>>(T3, cols, deg, out);
}